// Round 1
// baseline (302.582 us; speedup 1.0000x reference)
//
#include <hip/hip_runtime.h>
#include <hip/hip_bf16.h>
#include <stdint.h>

// ---- problem dims (fixed) ----
#define B_   8
#define S_   2048
#define D_   768
#define BS_  16384   // B_*S_
#define F_   1536    // 2*D_

typedef __attribute__((ext_vector_type(8))) short short8;   // 8 bf16 (4 VGPR) MFMA frag
typedef __attribute__((ext_vector_type(4))) float f32x4;    // MFMA acc frag
typedef __attribute__((ext_vector_type(4))) float float4v;
typedef __attribute__((ext_vector_type(4))) unsigned short ushort4v;

__device__ __forceinline__ unsigned short f2bf(float f) {
  union { float f; unsigned u; } v; v.f = f;
  unsigned r = v.u + 0x7FFFu + ((v.u >> 16) & 1u);   // RNE
  return (unsigned short)(r >> 16);
}
__device__ __forceinline__ float bf2f(unsigned short h) {
  union { unsigned u; float f; } v; v.u = ((unsigned)h) << 16;
  return v.f;
}

#define GLOAD16(gp, lp) \
  __builtin_amdgcn_global_load_lds((const __attribute__((address_space(1))) void*)(gp), \
                                   (__attribute__((address_space(3))) void*)(lp), 16, 0, 0)

// ---------------- cast kernels ----------------
__global__ __launch_bounds__(256) void k_cast(const float* __restrict__ src,
                                              unsigned short* __restrict__ dst, int n) {
  int i = (blockIdx.x * 256 + threadIdx.x) * 4;
  if (i >= n) return;
  float4v v = *(const float4v*)(src + i);
  ushort4v o;
  o[0] = f2bf(v[0]); o[1] = f2bf(v[1]); o[2] = f2bf(v[2]); o[3] = f2bf(v[3]);
  *(ushort4v*)(dst + i) = o;
}

// transformer_output -> fused[:, 0:768] (bf16)
__global__ __launch_bounds__(256) void k_cast_to_fused(const float* __restrict__ to,
                                                       unsigned short* __restrict__ fused) {
  int e = (blockIdx.x * 256 + threadIdx.x) * 4;
  if (e >= BS_ * D_) return;
  int r = e / D_, c = e % D_;            // c is a multiple of 4
  float4v v = *(const float4v*)(to + e);
  ushort4v o;
  o[0] = f2bf(v[0]); o[1] = f2bf(v[1]); o[2] = f2bf(v[2]); o[3] = f2bf(v[3]);
  *(ushort4v*)(fused + (size_t)r * F_ + c) = o;
}

// src[R][C] f32 -> dst[C][R] bf16   (R,C multiples of 32)
__global__ __launch_bounds__(256) void k_transpose_cast(const float* __restrict__ src,
                                                        unsigned short* __restrict__ dst,
                                                        int R, int C) {
  __shared__ float tile[32][33];
  int bx = blockIdx.x * 32;   // C index
  int by = blockIdx.y * 32;   // R index
  int tx = threadIdx.x, ty = threadIdx.y;   // block (32,8)
#pragma unroll
  for (int k = 0; k < 32; k += 8)
    tile[ty + k][tx] = src[(size_t)(by + ty + k) * C + bx + tx];
  __syncthreads();
#pragma unroll
  for (int k = 0; k < 32; k += 8)
    dst[(size_t)(bx + ty + k) * R + by + tx] = f2bf(tile[tx][ty + k]);
}

// ---------------- GEMM: C[M][768] = A[M][K] * BT[768][K]^T ----------------
// EPI=0: write f32 out + bias.  EPI=1: transpose-epilogue -> xpT[b][d][s] bf16.
template <int EPI>
__global__ __launch_bounds__(256) void k_gemm(const unsigned short* __restrict__ A,
                                              const unsigned short* __restrict__ BT,
                                              int K,
                                              float* __restrict__ outF,
                                              const float* __restrict__ bias,
                                              unsigned short* __restrict__ outT) {
  __shared__ unsigned short smem[(EPI == 1) ? 16384 : 8192];
  unsigned short* Alds = smem;          // [128][32]
  unsigned short* Blds = smem + 4096;   // [128][32]
  int nBase = blockIdx.x * 128;
  int mBase = blockIdx.y * 128;
  int t = threadIdx.x;
  int w = t >> 6, l = t & 63;
  int lm = l & 15, lg = l >> 4;
  int wm = w >> 1, wn = w & 1;   // 2x2 waves, 64x64 per wave
  f32x4 acc[4][4] = {};
  for (int kt = 0; kt < K; kt += 32) {
#pragma unroll
    for (int is = 0; is < 2; ++is) {
      int g = is * 256 + t;
      int row = g >> 2, k0 = (g & 3) * 8;
      GLOAD16(A  + (size_t)(mBase + row) * K + kt + k0, (char*)Alds + is * 4096 + w * 1024);
      GLOAD16(BT + (size_t)(nBase + row) * K + kt + k0, (char*)Blds + is * 4096 + w * 1024);
    }
    __syncthreads();
    short8 af[4], bfr[4];
#pragma unroll
    for (int mi = 0; mi < 4; ++mi)
      af[mi] = *(const short8*)(Alds + (wm * 64 + mi * 16 + lm) * 32 + lg * 8);
#pragma unroll
    for (int ni = 0; ni < 4; ++ni)
      bfr[ni] = *(const short8*)(Blds + (wn * 64 + ni * 16 + lm) * 32 + lg * 8);
#pragma unroll
    for (int mi = 0; mi < 4; ++mi)
#pragma unroll
      for (int ni = 0; ni < 4; ++ni)
        acc[mi][ni] = __builtin_amdgcn_mfma_f32_16x16x32_bf16(af[mi], bfr[ni], acc[mi][ni], 0, 0, 0);
    __syncthreads();
  }
  if (EPI == 0) {
#pragma unroll
    for (int mi = 0; mi < 4; ++mi) {
      int m = mBase + wm * 64 + mi * 16 + lg * 4;
#pragma unroll
      for (int ni = 0; ni < 4; ++ni) {
        int n = nBase + wn * 64 + ni * 16 + lm;
        float bv = bias[n];
#pragma unroll
        for (int r = 0; r < 4; ++r)
          outF[(size_t)(m + r) * 768 + n] = acc[mi][ni][r] + bv;
      }
    }
  } else {
    // write acc into smem as [n][m] (bf16), then store rows of xpT coalesced
#pragma unroll
    for (int mi = 0; mi < 4; ++mi) {
#pragma unroll
      for (int ni = 0; ni < 4; ++ni) {
        int nl = wn * 64 + ni * 16 + lm;
        int ml = wm * 64 + mi * 16 + lg * 4;
        ushort4v o;
        o[0] = f2bf(acc[mi][ni][0]); o[1] = f2bf(acc[mi][ni][1]);
        o[2] = f2bf(acc[mi][ni][2]); o[3] = f2bf(acc[mi][ni][3]);
        *(ushort4v*)(&smem[nl * 128 + ml]) = o;
      }
    }
    __syncthreads();
    int b = mBase >> 11;          // mBase / 2048 (block never straddles batches)
    int sBase = mBase & 2047;
#pragma unroll
    for (int it = 0; it < 8; ++it) {
      int nRow = it * 16 + (t >> 4);
      int m0 = (t & 15) * 8;
      short8 v = *(const short8*)(&smem[nRow * 128 + m0]);
      *(short8*)(outT + ((size_t)b * D_ + nBase + nRow) * S_ + sBase + m0) = v;
    }
  }
}

// ---------------- alphas: as/ad[b][s] = sum_d xpT[b][d][s] * a_{src,dst}[d] ----------------
__global__ __launch_bounds__(256) void k_alphas(const unsigned short* __restrict__ xpT,
                                                const float* __restrict__ a_src,
                                                const float* __restrict__ a_dst,
                                                float* __restrict__ as, float* __restrict__ ad) {
  int b = blockIdx.y;
  int s = blockIdx.x * 256 + threadIdx.x;
  const unsigned short* p = xpT + (size_t)b * D_ * S_ + s;
  float accs = 0.f, accd = 0.f;
  for (int d = 0; d < D_; ++d) {
    float v = bf2f(p[(size_t)d * S_]);
    accs = fmaf(a_src[d], v, accs);
    accd = fmaf(a_dst[d], v, accd);
  }
  as[b * S_ + s] = accs;
  ad[b * S_ + s] = accd;
}

// per-batch max of alpha_src
__global__ __launch_bounds__(256) void k_bmax(const float* __restrict__ as, float* __restrict__ Ms) {
  __shared__ float red[256];
  int b = blockIdx.x, t = threadIdx.x;
  float m = -1e30f;
#pragma unroll
  for (int k = 0; k < 8; ++k) m = fmaxf(m, as[b * S_ + t + k * 256]);
  red[t] = m;
  __syncthreads();
  for (int st = 128; st > 0; st >>= 1) {
    if (t < st) red[t] = fmaxf(red[t], red[t + st]);
    __syncthreads();
  }
  if (t == 0) Ms[b] = red[0];
}

// cc[b][i] = exp(-m_i)/l_i  with m_i = LRelu(d_i + Ms_b), l_i = sum_j exp(LRelu(d_i+s_j)-m_i)
__global__ __launch_bounds__(256) void k_stats(const float* __restrict__ as,
                                               const float* __restrict__ ad,
                                               const float* __restrict__ Ms,
                                               float* __restrict__ cc) {
  __shared__ float sj[S_];
  int b = blockIdx.y;
  int t = threadIdx.x;
#pragma unroll
  for (int k = 0; k < 8; ++k) sj[t + k * 256] = as[b * S_ + t + k * 256];
  __syncthreads();
  int i = blockIdx.x * 256 + t;
  float di = ad[b * S_ + i];
  float xm = di + Ms[b];
  float mi = fmaxf(xm, 0.2f * xm);
  float lsum = 0.f;
  for (int j = 0; j < S_; ++j) {
    float x = di + sj[j];
    float z = fmaxf(x, 0.2f * x);
    lsum += __expf(z - mi);
  }
  cc[b * S_ + i] = __expf(-mi) / lsum;
}

// ---------------- aggregation: fused[:,768:] = softmax(LRelu(d_i+s_j)) @ xp  (+ b_gat) ----------
__global__ __launch_bounds__(512) void k_agg(const unsigned short* __restrict__ xpT,
                                             const float* __restrict__ as,
                                             const float* __restrict__ ad,
                                             const float* __restrict__ cc,
                                             const float* __restrict__ b_gat,
                                             unsigned short* __restrict__ fused) {
  __shared__ unsigned short Blds[384 * 32];   // xpT tile [384 d][32 j], 24KB
  __shared__ float sj[S_];                    // 8KB
  int b  = blockIdx.z;
  int mB = blockIdx.x * 64;     // i block
  int nB = blockIdx.y * 384;    // d block
  int t = threadIdx.x;
  int w = t >> 6, l = t & 63;
  int lm = l & 15, lg = l >> 4;
  int wm = w & 3, wn = w >> 2;  // 4(m) x 2(n) waves, wave tile 16 x 192
  {
    float4v v = *(const float4v*)(as + b * S_ + t * 4);
    *(float4v*)(&sj[t * 4]) = v;
  }
  int iRow = mB + wm * 16 + lm;
  float di = ad[b * S_ + iRow];
  float ci = cc[b * S_ + iRow];
  const unsigned short* xpTb = xpT + (size_t)b * D_ * S_;
  f32x4 acc[12] = {};
  for (int jt = 0; jt < S_; jt += 32) {
#pragma unroll
    for (int is = 0; is < 3; ++is) {
      int g = is * 512 + t;
      int d = g >> 2, j0 = (g & 3) * 8;
      GLOAD16(xpTb + (size_t)(nB + d) * S_ + jt + j0, (char*)Blds + is * 8192 + w * 1024);
    }
    __syncthreads();
    // P fragment: rows i = mB+wm*16+lm, k = jt + lg*8 + u
    short8 pa;
#pragma unroll
    for (int u = 0; u < 8; ++u) {
      float s = sj[jt + lg * 8 + u];
      float x = di + s;
      float z = fmaxf(x, 0.2f * x);
      float p = __expf(z) * ci;           // already includes 1/l_i and e^{-m_i}
      pa[u] = (short)f2bf(p);
    }
#pragma unroll
    for (int ni = 0; ni < 12; ++ni) {
      short8 bfrag = *(const short8*)(Blds + (wn * 192 + ni * 16 + lm) * 32 + lg * 8);
      acc[ni] = __builtin_amdgcn_mfma_f32_16x16x32_bf16(pa, bfrag, acc[ni], 0, 0, 0);
    }
    __syncthreads();
  }
#pragma unroll
  for (int ni = 0; ni < 12; ++ni) {
    int dcol = nB + wn * 192 + ni * 16 + lm;
    float bg = b_gat[dcol];
#pragma unroll
    for (int r = 0; r < 4; ++r) {
      int m = mB + wm * 16 + lg * 4 + r;
      fused[(size_t)(b * S_ + m) * F_ + D_ + dcol] = f2bf(acc[ni][r] + bg);
    }
  }
}

// ---------------- launch ----------------
extern "C" void kernel_launch(void* const* d_in, const int* in_sizes, int n_in,
                              void* d_out, int out_size, void* d_ws, size_t ws_size,
                              hipStream_t stream) {
  const float* hs   = (const float*)d_in[0];
  const float* to   = (const float*)d_in[1];
  const float* Wg   = (const float*)d_in[2];
  const float* asrc = (const float*)d_in[3];
  const float* adst = (const float*)d_in[4];
  const float* bg   = (const float*)d_in[5];
  const float* Wf   = (const float*)d_in[6];
  const float* bfu  = (const float*)d_in[7];
  float* out = (float*)d_out;

  char* ws = (char*)d_ws;
  size_t off = 0;
  auto alloc = [&](size_t bytes) {
    char* p = ws + off;
    off += (bytes + 255) & ~(size_t)255;
    return p;
  };
  unsigned short* hs_bf = (unsigned short*)alloc((size_t)BS_ * D_ * 2);  // 25.2MB
  unsigned short* xpT   = (unsigned short*)alloc((size_t)B_ * D_ * S_ * 2); // 25.2MB
  unsigned short* fused = (unsigned short*)alloc((size_t)BS_ * F_ * 2);  // 50.3MB
  unsigned short* WgT   = (unsigned short*)alloc((size_t)D_ * D_ * 2);
  unsigned short* WfT   = (unsigned short*)alloc((size_t)D_ * F_ * 2);
  float* as = (float*)alloc((size_t)BS_ * 4);
  float* ad = (float*)alloc((size_t)BS_ * 4);
  float* cc = (float*)alloc((size_t)BS_ * 4);
  float* Ms = (float*)alloc(256);

  int n = BS_ * D_;
  k_cast<<<n / 1024, 256, 0, stream>>>(hs, hs_bf, n);
  k_cast_to_fused<<<n / 1024, 256, 0, stream>>>(to, fused);
  k_transpose_cast<<<dim3(D_ / 32, D_ / 32), dim3(32, 8), 0, stream>>>(Wg, WgT, D_, D_);
  k_transpose_cast<<<dim3(D_ / 32, F_ / 32), dim3(32, 8), 0, stream>>>(Wf, WfT, F_, D_);
  k_gemm<1><<<dim3(6, 128), 256, 0, stream>>>(hs_bf, WgT, D_, nullptr, nullptr, xpT);
  k_alphas<<<dim3(8, B_), 256, 0, stream>>>(xpT, asrc, adst, as, ad);
  k_bmax<<<B_, 256, 0, stream>>>(as, Ms);
  k_stats<<<dim3(8, B_), 256, 0, stream>>>(as, ad, Ms, cc);
  k_agg<<<dim3(32, 2, B_), 512, 0, stream>>>(xpT, as, ad, cc, bg, fused);
  k_gemm<0><<<dim3(6, 128), 256, 0, stream>>>(fused, WfT, F_, out, bfu, nullptr);
}

// Round 2
// 263.733 us; speedup vs baseline: 1.1473x; 1.1473x over previous
//
#include <hip/hip_runtime.h>
#include <hip/hip_bf16.h>
#include <stdint.h>

// ---- problem dims (fixed) ----
#define B_   8
#define S_   2048
#define D_   768
#define BS_  16384   // B_*S_
#define F_   1536    // 2*D_

typedef __attribute__((ext_vector_type(8))) short short8;   // 8 bf16 (4 VGPR) MFMA frag
typedef __attribute__((ext_vector_type(4))) float f32x4;    // MFMA acc frag
typedef __attribute__((ext_vector_type(4))) float float4v;
typedef __attribute__((ext_vector_type(4))) unsigned short ushort4v;

__device__ __forceinline__ unsigned short f2bf(float f) {
  union { float f; unsigned u; } v; v.f = f;
  unsigned r = v.u + 0x7FFFu + ((v.u >> 16) & 1u);   // RNE
  return (unsigned short)(r >> 16);
}
__device__ __forceinline__ float bf2f(unsigned short h) {
  union { unsigned u; float f; } v; v.u = ((unsigned)h) << 16;
  return v.f;
}

#define GLOAD16(gp, lp) \
  __builtin_amdgcn_global_load_lds((const __attribute__((address_space(1))) void*)(gp), \
                                   (__attribute__((address_space(3))) void*)(lp), 16, 0, 0)

// ---------------- cast kernels ----------------
__global__ __launch_bounds__(256) void k_cast(const float* __restrict__ src,
                                              unsigned short* __restrict__ dst, int n) {
  int i = (blockIdx.x * 256 + threadIdx.x) * 4;
  if (i >= n) return;
  float4v v = *(const float4v*)(src + i);
  ushort4v o;
  o[0] = f2bf(v[0]); o[1] = f2bf(v[1]); o[2] = f2bf(v[2]); o[3] = f2bf(v[3]);
  *(ushort4v*)(dst + i) = o;
}

// transformer_output -> fused[:, 0:768] (bf16)
__global__ __launch_bounds__(256) void k_cast_to_fused(const float* __restrict__ to,
                                                       unsigned short* __restrict__ fused) {
  int e = (blockIdx.x * 256 + threadIdx.x) * 4;
  if (e >= BS_ * D_) return;
  int r = e / D_, c = e % D_;            // c is a multiple of 4
  float4v v = *(const float4v*)(to + e);
  ushort4v o;
  o[0] = f2bf(v[0]); o[1] = f2bf(v[1]); o[2] = f2bf(v[2]); o[3] = f2bf(v[3]);
  *(ushort4v*)(fused + (size_t)r * F_ + c) = o;
}

// src[R][C] f32 -> dst[C][R] bf16   (R,C multiples of 32)
__global__ __launch_bounds__(256) void k_transpose_cast(const float* __restrict__ src,
                                                        unsigned short* __restrict__ dst,
                                                        int R, int C) {
  __shared__ float tile[32][33];
  int bx = blockIdx.x * 32;   // C index
  int by = blockIdx.y * 32;   // R index
  int tx = threadIdx.x, ty = threadIdx.y;   // block (32,8)
#pragma unroll
  for (int k = 0; k < 32; k += 8)
    tile[ty + k][tx] = src[(size_t)(by + ty + k) * C + bx + tx];
  __syncthreads();
#pragma unroll
  for (int k = 0; k < 32; k += 8)
    dst[(size_t)(bx + ty + k) * R + by + tx] = f2bf(tile[tx][ty + k]);
}

// ---------------- GEMM: C[M][768] = A[M][K] * BT[768][K]^T ----------------
// 4-slot XOR swizzle on staging source + LDS reads: 8-way -> 4-way bank conflicts.
// EPI=0: write f32 out + bias.  EPI=1: transpose-epilogue -> xpT[b][d][s] bf16.
template <int EPI>
__global__ __launch_bounds__(256) void k_gemm(const unsigned short* __restrict__ A,
                                              const unsigned short* __restrict__ BT,
                                              int K,
                                              float* __restrict__ outF,
                                              const float* __restrict__ bias,
                                              unsigned short* __restrict__ outT) {
  __shared__ unsigned short smem[(EPI == 1) ? 16384 : 8192];
  unsigned short* Alds = smem;          // [128][32]
  unsigned short* Blds = smem + 4096;   // [128][32]
  int nBase = blockIdx.x * 128;
  int mBase = blockIdx.y * 128;
  int t = threadIdx.x;
  int w = t >> 6, l = t & 63;
  int lm = l & 15, lg = l >> 4;
  int wm = w >> 1, wn = w & 1;   // 2x2 waves, 64x64 per wave
  f32x4 acc[4][4] = {};
  for (int kt = 0; kt < K; kt += 32) {
#pragma unroll
    for (int is = 0; is < 2; ++is) {
      int g = is * 256 + t;
      int row = g >> 2, k0 = ((g & 3) ^ (row & 3)) * 8;   // pre-swizzled source
      GLOAD16(A  + (size_t)(mBase + row) * K + kt + k0, (char*)Alds + is * 4096 + w * 1024);
      GLOAD16(BT + (size_t)(nBase + row) * K + kt + k0, (char*)Blds + is * 4096 + w * 1024);
    }
    __syncthreads();
    short8 af[4], bfr[4];
#pragma unroll
    for (int mi = 0; mi < 4; ++mi)
      af[mi] = *(const short8*)(Alds + (wm * 64 + mi * 16 + lm) * 32 + ((lg ^ (lm & 3)) * 8));
#pragma unroll
    for (int ni = 0; ni < 4; ++ni)
      bfr[ni] = *(const short8*)(Blds + (wn * 64 + ni * 16 + lm) * 32 + ((lg ^ (lm & 3)) * 8));
#pragma unroll
    for (int mi = 0; mi < 4; ++mi)
#pragma unroll
      for (int ni = 0; ni < 4; ++ni)
        acc[mi][ni] = __builtin_amdgcn_mfma_f32_16x16x32_bf16(af[mi], bfr[ni], acc[mi][ni], 0, 0, 0);
    __syncthreads();
  }
  if (EPI == 0) {
#pragma unroll
    for (int mi = 0; mi < 4; ++mi) {
      int m = mBase + wm * 64 + mi * 16 + lg * 4;
#pragma unroll
      for (int ni = 0; ni < 4; ++ni) {
        int n = nBase + wn * 64 + ni * 16 + lm;
        float bv = bias[n];
#pragma unroll
        for (int r = 0; r < 4; ++r)
          outF[(size_t)(m + r) * 768 + n] = acc[mi][ni][r] + bv;
      }
    }
  } else {
    // write acc into smem as [n][m] (bf16), then store rows of xpT coalesced
#pragma unroll
    for (int mi = 0; mi < 4; ++mi) {
#pragma unroll
      for (int ni = 0; ni < 4; ++ni) {
        int nl = wn * 64 + ni * 16 + lm;
        int ml = wm * 64 + mi * 16 + lg * 4;
        ushort4v o;
        o[0] = f2bf(acc[mi][ni][0]); o[1] = f2bf(acc[mi][ni][1]);
        o[2] = f2bf(acc[mi][ni][2]); o[3] = f2bf(acc[mi][ni][3]);
        *(ushort4v*)(&smem[nl * 128 + ml]) = o;
      }
    }
    __syncthreads();
    int b = mBase >> 11;          // mBase / 2048 (block never straddles batches)
    int sBase = mBase & 2047;
#pragma unroll
    for (int it = 0; it < 8; ++it) {
      int nRow = it * 16 + (t >> 4);
      int m0 = (t & 15) * 8;
      short8 v = *(const short8*)(&smem[nRow * 128 + m0]);
      *(short8*)(outT + ((size_t)b * D_ + nBase + nRow) * S_ + sBase + m0) = v;
    }
  }
}

// ---------------- alphas: as/ad[b][s] = sum_d xpT[b][d][s] * a_{src,dst}[d] ----------------
__global__ __launch_bounds__(256) void k_alphas(const unsigned short* __restrict__ xpT,
                                                const float* __restrict__ a_src,
                                                const float* __restrict__ a_dst,
                                                float* __restrict__ as, float* __restrict__ ad) {
  __shared__ float rs[4][64], rd[4][64];
  int b = blockIdx.y;
  int sl = threadIdx.x & 63, part = threadIdx.x >> 6;
  int s = blockIdx.x * 64 + sl;
  const unsigned short* p = xpT + (size_t)b * D_ * S_ + s;
  float accs = 0.f, accd = 0.f;
  for (int d = part * 192; d < part * 192 + 192; ++d) {
    float v = bf2f(p[(size_t)d * S_]);
    accs = fmaf(a_src[d], v, accs);
    accd = fmaf(a_dst[d], v, accd);
  }
  rs[part][sl] = accs; rd[part][sl] = accd;
  __syncthreads();
  if (threadIdx.x < 64) {
    int tt = threadIdx.x;
    as[b * S_ + blockIdx.x * 64 + tt] = rs[0][tt] + rs[1][tt] + rs[2][tt] + rs[3][tt];
    ad[b * S_ + blockIdx.x * 64 + tt] = rd[0][tt] + rd[1][tt] + rd[2][tt] + rd[3][tt];
  }
}

// per-batch max of alpha_src
__global__ __launch_bounds__(256) void k_bmax(const float* __restrict__ as, float* __restrict__ Ms) {
  __shared__ float red[256];
  int b = blockIdx.x, t = threadIdx.x;
  float m = -1e30f;
#pragma unroll
  for (int k = 0; k < 8; ++k) m = fmaxf(m, as[b * S_ + t + k * 256]);
  red[t] = m;
  __syncthreads();
  for (int st = 128; st > 0; st >>= 1) {
    if (t < st) red[t] = fmaxf(red[t], red[t + st]);
    __syncthreads();
  }
  if (t == 0) Ms[b] = red[0];
}

// cc[b][i] = exp(-m_i)/l_i ; 64 i per block, j-loop split 4 ways
__global__ __launch_bounds__(256) void k_stats(const float* __restrict__ as,
                                               const float* __restrict__ ad,
                                               const float* __restrict__ Ms,
                                               float* __restrict__ cc) {
  __shared__ float sjl[S_];
  __shared__ float red[4][64];
  int b = blockIdx.y;
  int t = threadIdx.x;
#pragma unroll
  for (int k = 0; k < 8; ++k) sjl[t + k * 256] = as[b * S_ + t + k * 256];
  __syncthreads();
  int il = t & 63, part = t >> 6;
  int i = blockIdx.x * 64 + il;
  float di = ad[b * S_ + i];
  float xm = di + Ms[b];
  float mi = fmaxf(xm, 0.2f * xm);
  float lsum = 0.f;
  for (int j = part * 512; j < part * 512 + 512; ++j) {
    float x = di + sjl[j];
    float z = fmaxf(x, 0.2f * x);
    lsum += __expf(z - mi);
  }
  red[part][il] = lsum;
  __syncthreads();
  if (t < 64) {
    float lt = red[0][t] + red[1][t] + red[2][t] + red[3][t];
    cc[b * S_ + blockIdx.x * 64 + t] = __expf(-mi) / lt;   // t<64 => part==0, own mi
  }
}

// ---------------- aggregation v3: GEMM-structured, swizzled, double-buffered ------------
// Block 512 thr (8 waves: 2m x 4n). Tile 128 i x 384 d, BK=64. Wave: 64i x 96d (M4 x N6).
// P[128][64] computed once per block into LDS (shared by all waves). XOR swizzle
// slot ^= (row&7) on both producer and consumer sides. Dynamic LDS 136KB, 1 block/CU.
__global__ __launch_bounds__(512, 2) void k_agg(const unsigned short* __restrict__ xpT,
                                                const float* __restrict__ as,
                                                const float* __restrict__ ad,
                                                const float* __restrict__ cc,
                                                const float* __restrict__ b_gat,
                                                unsigned short* __restrict__ fused) {
  extern __shared__ char dynlds[];
  unsigned short* X0 = (unsigned short*)dynlds;      // [384][64]
  unsigned short* X1 = X0 + 384 * 64;
  unsigned short* P0 = X1 + 384 * 64;                // [128][64]
  unsigned short* P1 = P0 + 128 * 64;
  float* sj = (float*)(P1 + 128 * 64);               // [2048]

  int bid = blockIdx.x;          // 256 blocks; bid&7 = batch -> one batch per XCD (L2 locality)
  int b = bid & 7;
  int within = bid >> 3;
  int mB = (within & 15) * 128;
  int dB = (within >> 4) * 384;

  int t = threadIdx.x;
  int w = t >> 6, l = t & 63;
  int lm = l & 15, lg = l >> 4;
  int wm = w >> 2, wn = w & 3;

  // stage alpha_src row into LDS
  { float4v v = *(const float4v*)(as + b * S_ + t * 4); *(float4v*)(sj + t * 4) = v; }

  // P-producer constants: thread t handles P row iP, two 8-elem slots
  int iP = t >> 2;                       // 0..127
  float di = ad[b * S_ + mB + iP];
  float ci = cc[b * S_ + mB + iP];
  int s0 = (t & 3) | ((iP & 1) << 2);    // write-conflict-spread slot assignment

  const unsigned short* Xsrc = xpT + (size_t)b * D_ * S_ + (size_t)dB * S_;

  auto stage = [&](int jt, char* Xb) {
#pragma unroll
    for (int is = 0; is < 6; ++is) {
      int g = is * 512 + t;
      int d = g >> 3, p = g & 7;
      GLOAD16(Xsrc + (size_t)d * S_ + jt + ((p ^ (d & 7)) * 8), Xb + is * 8192 + w * 1024);
    }
  };
  auto pgen = [&](int jt, unsigned short* Pb) {
#pragma unroll
    for (int ss = 0; ss < 2; ++ss) {
      int sph = ss ? (s0 ^ 4) : s0;
      int jc = sph ^ (iP & 7);
      int j0 = jt + jc * 8;
      float sv[8];
      *(float4v*)(sv)     = *(const float4v*)(sj + j0);
      *(float4v*)(sv + 4) = *(const float4v*)(sj + j0 + 4);
      union { short8 v; unsigned short us[8]; } pk;
#pragma unroll
      for (int q = 0; q < 8; ++q) {
        float x = di + sv[q];
        float z = fmaxf(x, 0.2f * x);
        pk.us[q] = f2bf(__expf(z) * ci);   // includes e^{-m_i}/l_i via ci
      }
      *(short8*)(Pb + iP * 64 + sph * 8) = pk.v;
    }
  };

  __syncthreads();                 // sj visible before pgen
  f32x4 acc[4][6] = {};
  stage(0, (char*)X0);
  pgen(0, P0);
  __syncthreads();                 // drains vmcnt too

  for (int tt = 0; tt < 32; ++tt) {
    unsigned short* Xc = (tt & 1) ? X1 : X0;
    unsigned short* Pc = (tt & 1) ? P1 : P0;
    if (tt < 31) {
      stage((tt + 1) * 64, (char*)((tt & 1) ? X0 : X1));
      pgen((tt + 1) * 64, (tt & 1) ? P0 : P1);
    }
#pragma unroll
    for (int kk = 0; kk < 2; ++kk) {
      int kc = kk * 4 + lg;
      short8 af[4], bfv[6];
#pragma unroll
      for (int mi = 0; mi < 4; ++mi) {
        int row = wm * 64 + mi * 16 + lm;
        af[mi] = *(const short8*)(Pc + row * 64 + ((kc ^ (row & 7)) * 8));
      }
#pragma unroll
      for (int ni = 0; ni < 6; ++ni) {
        int row = wn * 96 + ni * 16 + lm;
        bfv[ni] = *(const short8*)(Xc + row * 64 + ((kc ^ (row & 7)) * 8));
      }
#pragma unroll
      for (int mi = 0; mi < 4; ++mi)
#pragma unroll
        for (int ni = 0; ni < 6; ++ni)
          acc[mi][ni] = __builtin_amdgcn_mfma_f32_16x16x32_bf16(af[mi], bfv[ni], acc[mi][ni], 0, 0, 0);
    }
    __syncthreads();
  }

  // epilogue: direct stores (cols per quarter-wave are 16 consecutive bf16)
#pragma unroll
  for (int ni = 0; ni < 6; ++ni) {
    int col = dB + wn * 96 + ni * 16 + lm;
    float bg = b_gat[col];
#pragma unroll
    for (int mi = 0; mi < 4; ++mi) {
      int m = mB + wm * 64 + mi * 16 + lg * 4;
#pragma unroll
      for (int r = 0; r < 4; ++r)
        fused[(size_t)(b * S_ + m + r) * F_ + D_ + col] = f2bf(acc[mi][ni][r] + bg);
    }
  }
}

// ---------------- launch ----------------
extern "C" void kernel_launch(void* const* d_in, const int* in_sizes, int n_in,
                              void* d_out, int out_size, void* d_ws, size_t ws_size,
                              hipStream_t stream) {
  const float* hs   = (const float*)d_in[0];
  const float* to   = (const float*)d_in[1];
  const float* Wg   = (const float*)d_in[2];
  const float* asrc = (const float*)d_in[3];
  const float* adst = (const float*)d_in[4];
  const float* bg   = (const float*)d_in[5];
  const float* Wf   = (const float*)d_in[6];
  const float* bfu  = (const float*)d_in[7];
  float* out = (float*)d_out;

  char* ws = (char*)d_ws;
  size_t off = 0;
  auto alloc = [&](size_t bytes) {
    char* p = ws + off;
    off += (bytes + 255) & ~(size_t)255;
    return p;
  };
  unsigned short* hs_bf = (unsigned short*)alloc((size_t)BS_ * D_ * 2);
  unsigned short* xpT   = (unsigned short*)alloc((size_t)B_ * D_ * S_ * 2);
  unsigned short* fused = (unsigned short*)alloc((size_t)BS_ * F_ * 2);
  unsigned short* WgT   = (unsigned short*)alloc((size_t)D_ * D_ * 2);
  unsigned short* WfT   = (unsigned short*)alloc((size_t)D_ * F_ * 2);
  float* as = (float*)alloc((size_t)BS_ * 4);
  float* ad = (float*)alloc((size_t)BS_ * 4);
  float* cc = (float*)alloc((size_t)BS_ * 4);
  float* Ms = (float*)alloc(256);

  int n = BS_ * D_;
  k_cast<<<n / 1024, 256, 0, stream>>>(hs, hs_bf, n);
  k_cast_to_fused<<<n / 1024, 256, 0, stream>>>(to, fused);
  k_transpose_cast<<<dim3(D_ / 32, D_ / 32), dim3(32, 8), 0, stream>>>(Wg, WgT, D_, D_);
  k_transpose_cast<<<dim3(D_ / 32, F_ / 32), dim3(32, 8), 0, stream>>>(Wf, WfT, F_, D_);
  k_gemm<1><<<dim3(6, 128), 256, 0, stream>>>(hs_bf, WgT, D_, nullptr, nullptr, xpT);
  k_alphas<<<dim3(32, B_), 256, 0, stream>>>(xpT, asrc, adst, as, ad);
  k_bmax<<<B_, 256, 0, stream>>>(as, Ms);
  k_stats<<<dim3(32, B_), 256, 0, stream>>>(as, ad, Ms, cc);
  (void)hipFuncSetAttribute((const void*)k_agg,
                            hipFuncAttributeMaxDynamicSharedMemorySize, 139264);
  k_agg<<<256, 512, 139264, stream>>>(xpT, as, ad, cc, bg, fused);
  k_gemm<0><<<dim3(6, 128), 256, 0, stream>>>(fused, WfT, F_, out, bfu, nullptr);
}

// Round 3
// 252.897 us; speedup vs baseline: 1.1965x; 1.0428x over previous
//
#include <hip/hip_runtime.h>
#include <hip/hip_bf16.h>
#include <stdint.h>

// ---- problem dims (fixed) ----
#define B_   8
#define S_   2048
#define D_   768
#define BS_  16384   // B_*S_
#define F_   1536    // 2*D_
#define L2E  1.4426950408889634f

typedef __attribute__((ext_vector_type(8))) short short8;    // 8 bf16 MFMA frag
typedef __attribute__((ext_vector_type(4))) float f32x4;     // 16x16 acc frag
typedef __attribute__((ext_vector_type(16))) float f32x16;   // 32x32 acc frag
typedef __attribute__((ext_vector_type(4))) float float4v;
typedef __attribute__((ext_vector_type(4))) unsigned short ushort4v;

__device__ __forceinline__ unsigned short f2bf(float f) {
  union { float f; unsigned u; } v; v.f = f;
  unsigned r = v.u + 0x7FFFu + ((v.u >> 16) & 1u);   // RNE
  return (unsigned short)(r >> 16);
}
__device__ __forceinline__ float exp2_fast(float x) {
  float r; asm("v_exp_f32 %0, %1" : "=v"(r) : "v"(x)); return r;
}
__device__ __forceinline__ unsigned cvtpk_bf16(float lo, float hi) {
  unsigned r; asm("v_cvt_pk_bf16_f32 %0, %1, %2" : "=v"(r) : "v"(lo), "v"(hi)); return r;
}

#define GLOAD16(gp, lp) \
  __builtin_amdgcn_global_load_lds((const __attribute__((address_space(1))) void*)(gp), \
                                   (__attribute__((address_space(3))) void*)(lp), 16, 0, 0)

// ---------------- cast kernels (8 elem/thread) ----------------
__global__ __launch_bounds__(256) void k_cast8(const float* __restrict__ src,
                                               unsigned short* __restrict__ dst, int n) {
  int i = (blockIdx.x * 256 + threadIdx.x) * 8;
  if (i >= n) return;
  float4v a = *(const float4v*)(src + i);
  float4v b2 = *(const float4v*)(src + i + 4);
  union { short8 s; unsigned u[4]; } o;
  o.u[0] = cvtpk_bf16(a[0], a[1]); o.u[1] = cvtpk_bf16(a[2], a[3]);
  o.u[2] = cvtpk_bf16(b2[0], b2[1]); o.u[3] = cvtpk_bf16(b2[2], b2[3]);
  *(short8*)(dst + i) = o.s;
}

__global__ __launch_bounds__(256) void k_cast_to_fused8(const float* __restrict__ to,
                                                        unsigned short* __restrict__ fused) {
  int e = (blockIdx.x * 256 + threadIdx.x) * 8;
  if (e >= BS_ * D_) return;
  int r = e / D_, c = e % D_;            // c multiple of 8
  float4v a = *(const float4v*)(to + e);
  float4v b2 = *(const float4v*)(to + e + 4);
  union { short8 s; unsigned u[4]; } o;
  o.u[0] = cvtpk_bf16(a[0], a[1]); o.u[1] = cvtpk_bf16(a[2], a[3]);
  o.u[2] = cvtpk_bf16(b2[0], b2[1]); o.u[3] = cvtpk_bf16(b2[2], b2[3]);
  *(short8*)(fused + (size_t)r * F_ + c) = o.s;
}

// src[R][C] f32 -> dst[C][R] bf16   (R,C multiples of 32)
__global__ __launch_bounds__(256) void k_transpose_cast(const float* __restrict__ src,
                                                        unsigned short* __restrict__ dst,
                                                        int R, int C) {
  __shared__ float tile[32][33];
  int bx = blockIdx.x * 32;   // C index
  int by = blockIdx.y * 32;   // R index
  int tx = threadIdx.x, ty = threadIdx.y;   // block (32,8)
#pragma unroll
  for (int k = 0; k < 32; k += 8)
    tile[ty + k][tx] = src[(size_t)(by + ty + k) * C + bx + tx];
  __syncthreads();
#pragma unroll
  for (int k = 0; k < 32; k += 8)
    dst[(size_t)(bx + ty + k) * R + by + tx] = f2bf(tile[tx][ty + k]);
}

// ---------------- GEMM: C[M][768] = A[M][K] * BT[768][K]^T ----------------
// XCD-chunk block swizzle + (row>>1)&3 slot swizzle. EPI=0: f32 out + bias.
// EPI=1: transpose-epilogue -> xpT[b][d][s] bf16.
template <int EPI>
__global__ __launch_bounds__(256) void k_gemm(const unsigned short* __restrict__ A,
                                              const unsigned short* __restrict__ BT,
                                              int K,
                                              float* __restrict__ outF,
                                              const float* __restrict__ bias,
                                              unsigned short* __restrict__ outT) {
  __shared__ unsigned short smem[(EPI == 1) ? 16384 : 8192];
  unsigned short* Alds = smem;          // [128][32]
  unsigned short* Blds = smem + 4096;   // [128][32]
  int lin = blockIdx.y * 6 + blockIdx.x;          // 768 blocks
  int nl  = (lin & 7) * 96 + (lin >> 3);          // 96 contiguous per XCD
  int nBase = (nl % 6) * 128;
  int mBase = (nl / 6) * 128;
  int t = threadIdx.x;
  int w = t >> 6, l = t & 63;
  int lm = l & 15, lg = l >> 4;
  int wm = w >> 1, wn = w & 1;   // 2x2 waves, 64x64 per wave
  f32x4 acc[4][4] = {};
  for (int kt = 0; kt < K; kt += 32) {
#pragma unroll
    for (int is = 0; is < 2; ++is) {
      int g = is * 256 + t;
      int row = g >> 2, k0 = ((g & 3) ^ ((row >> 1) & 3)) * 8;   // pre-swizzled source
      GLOAD16(A  + (size_t)(mBase + row) * K + kt + k0, (char*)Alds + is * 4096 + w * 1024);
      GLOAD16(BT + (size_t)(nBase + row) * K + kt + k0, (char*)Blds + is * 4096 + w * 1024);
    }
    __syncthreads();
    int sl = (lg ^ ((lm >> 1) & 3)) * 8;
    short8 af[4], bfr[4];
#pragma unroll
    for (int mi = 0; mi < 4; ++mi)
      af[mi] = *(const short8*)(Alds + (wm * 64 + mi * 16 + lm) * 32 + sl);
#pragma unroll
    for (int ni = 0; ni < 4; ++ni)
      bfr[ni] = *(const short8*)(Blds + (wn * 64 + ni * 16 + lm) * 32 + sl);
#pragma unroll
    for (int mi = 0; mi < 4; ++mi)
#pragma unroll
      for (int ni = 0; ni < 4; ++ni)
        acc[mi][ni] = __builtin_amdgcn_mfma_f32_16x16x32_bf16(af[mi], bfr[ni], acc[mi][ni], 0, 0, 0);
    __syncthreads();
  }
  if (EPI == 0) {
#pragma unroll
    for (int mi = 0; mi < 4; ++mi) {
      int m = mBase + wm * 64 + mi * 16 + lg * 4;
#pragma unroll
      for (int ni = 0; ni < 4; ++ni) {
        int n = nBase + wn * 64 + ni * 16 + lm;
        float bv = bias[n];
#pragma unroll
        for (int r = 0; r < 4; ++r)
          outF[(size_t)(m + r) * 768 + n] = acc[mi][ni][r] + bv;
      }
    }
  } else {
#pragma unroll
    for (int mi = 0; mi < 4; ++mi) {
#pragma unroll
      for (int ni = 0; ni < 4; ++ni) {
        int nl2 = wn * 64 + ni * 16 + lm;
        int ml = wm * 64 + mi * 16 + lg * 4;
        ushort4v o;
        o[0] = f2bf(acc[mi][ni][0]); o[1] = f2bf(acc[mi][ni][1]);
        o[2] = f2bf(acc[mi][ni][2]); o[3] = f2bf(acc[mi][ni][3]);
        *(ushort4v*)(&smem[nl2 * 128 + ml]) = o;
      }
    }
    __syncthreads();
    int b = mBase >> 11;
    int sBase = mBase & 2047;
#pragma unroll
    for (int it = 0; it < 8; ++it) {
      int nRow = it * 16 + (t >> 4);
      int m0 = (t & 15) * 8;
      short8 v = *(const short8*)(&smem[nRow * 128 + m0]);
      *(short8*)(outT + ((size_t)b * D_ + nBase + nRow) * S_ + sBase + m0) = v;
    }
  }
}

// ---------------- alphas ----------------
__global__ __launch_bounds__(256) void k_alphas(const unsigned short* __restrict__ xpT,
                                                const float* __restrict__ a_src,
                                                const float* __restrict__ a_dst,
                                                float* __restrict__ as, float* __restrict__ ad) {
  __shared__ float rs[4][64], rd[4][64];
  int b = blockIdx.y;
  int sl = threadIdx.x & 63, part = threadIdx.x >> 6;
  int s = blockIdx.x * 64 + sl;
  const unsigned short* p = xpT + (size_t)b * D_ * S_ + s;
  float accs = 0.f, accd = 0.f;
  for (int d = part * 192; d < part * 192 + 192; ++d) {
    union { unsigned u; float f; } v; v.u = ((unsigned)p[(size_t)d * S_]) << 16;
    accs = fmaf(a_src[d], v.f, accs);
    accd = fmaf(a_dst[d], v.f, accd);
  }
  rs[part][sl] = accs; rd[part][sl] = accd;
  __syncthreads();
  if (threadIdx.x < 64) {
    int tt = threadIdx.x;
    as[b * S_ + blockIdx.x * 64 + tt] = rs[0][tt] + rs[1][tt] + rs[2][tt] + rs[3][tt];
    ad[b * S_ + blockIdx.x * 64 + tt] = rd[0][tt] + rd[1][tt] + rd[2][tt] + rd[3][tt];
  }
}

// per-batch max of alpha_src
__global__ __launch_bounds__(256) void k_bmax(const float* __restrict__ as, float* __restrict__ Ms) {
  __shared__ float red[256];
  int b = blockIdx.x, t = threadIdx.x;
  float m = -1e30f;
#pragma unroll
  for (int k = 0; k < 8; ++k) m = fmaxf(m, as[b * S_ + t + k * 256]);
  red[t] = m;
  __syncthreads();
  for (int st = 128; st > 0; st >>= 1) {
    if (t < st) red[t] = fmaxf(red[t], red[t + st]);
    __syncthreads();
  }
  if (t == 0) Ms[b] = red[0];
}

// stats: ccA=(d_i-m_i)*L2E, ccB=(0.2d_i-m_i)*L2E, il=1/l_i, aslg=as*L2E
__global__ __launch_bounds__(256) void k_stats(const float* __restrict__ as,
                                               const float* __restrict__ ad,
                                               const float* __restrict__ Ms,
                                               float* __restrict__ ccA, float* __restrict__ ccB,
                                               float* __restrict__ il, float* __restrict__ aslg) {
  __shared__ float sjl[S_];
  __shared__ float red[4][64];
  int b = blockIdx.y;
  int t = threadIdx.x;
#pragma unroll
  for (int k = 0; k < 8; ++k) sjl[t + k * 256] = as[b * S_ + t + k * 256];
  __syncthreads();
  int ilc = t & 63, part = t >> 6;
  int i = blockIdx.x * 64 + ilc;
  float di = ad[b * S_ + i];
  float xm = di + Ms[b];
  float mi = fmaxf(xm, 0.2f * xm);
  float lsum = 0.f;
  for (int j = part * 512; j < part * 512 + 512; ++j) {
    float x = di + sjl[j];
    float z = fmaxf(x, 0.2f * x);
    lsum += __expf(z - mi);
  }
  red[part][ilc] = lsum;
  __syncthreads();
  if (t < 64) {
    int ig = blockIdx.x * 64 + t;      // part==0 -> own di, mi valid
    float lt = red[0][t] + red[1][t] + red[2][t] + red[3][t];
    il[b * S_ + ig] = 1.0f / lt;
    ccA[b * S_ + ig] = (di - mi) * L2E;
    ccB[b * S_ + ig] = fmaf(0.2f, di, -mi) * L2E;
    aslg[b * S_ + ig] = sjl[ig] * L2E;
  }
}

// ---------------- aggregation v4: 32x32 MFMA, 2 blocks/CU ----------------
// 256 thr (4 waves 2m x 2n), wave 64i x 96d (M2 x N3 of 32x32x16), block 128i x 192d,
// BK=32, X/P double-buffered, (row>>1)&3 slot swizzle both sides. LDS 48.5KB static.
__global__ __launch_bounds__(256, 2) void k_agg(const unsigned short* __restrict__ xpT,
                                                const float* __restrict__ ccA,
                                                const float* __restrict__ ccB,
                                                const float* __restrict__ ilg,
                                                const float* __restrict__ aslg,
                                                const float* __restrict__ b_gat,
                                                unsigned short* __restrict__ fused) {
  __shared__ unsigned short X0[192 * 32], X1[192 * 32];   // 12KB each
  __shared__ unsigned short P0[128 * 32], P1[128 * 32];   // 8KB each
  __shared__ float sj[S_];                                 // 8KB
  __shared__ float ilds[128];

  int bid = blockIdx.x;          // 512 blocks; bid&7 = batch (one batch per XCD)
  int b = bid & 7;
  int within = bid >> 3;         // 0..63
  int mB = (within & 15) * 128;
  int dB = (within >> 4) * 192;

  int t = threadIdx.x;
  int w = t >> 6, l = t & 63;
  int lr = l & 31, lh = l >> 5;
  int wm = w >> 1, wn = w & 1;   // wave: i [wm*64,+64), d [wn*96,+96)

  // stage scaled alpha_src row + 1/l tile
  {
    float4v v0 = *(const float4v*)(aslg + b * S_ + t * 8);
    float4v v1 = *(const float4v*)(aslg + b * S_ + t * 8 + 4);
    *(float4v*)(sj + t * 8) = v0;
    *(float4v*)(sj + t * 8 + 4) = v1;
    if (t < 128) ilds[t] = ilg[b * S_ + mB + t];
  }

  int iP = t >> 1;                       // P row 0..127
  float Ar = ccA[b * S_ + mB + iP];
  float Br = ccB[b * S_ + mB + iP];

  const unsigned short* Xsrc = xpT + (size_t)b * D_ * S_ + (size_t)dB * S_;

  auto stage = [&](int jt, char* Xb) {
#pragma unroll
    for (int is = 0; is < 3; ++is) {
      int g = is * 256 + t;            // 0..767 (192 rows x 4 slots)
      int r = g >> 2, p = g & 3;
      int c = p ^ ((r >> 1) & 3);      // logical j-chunk for this physical slot
      GLOAD16(Xsrc + (size_t)r * S_ + jt + c * 8, Xb + is * 4096 + w * 1024);
    }
  };
  auto pgen = [&](int jt, unsigned short* Pb) {
#pragma unroll
    for (int cs = 0; cs < 2; ++cs) {
      int c = (t & 1) * 2 + cs;        // logical chunk
      int j0 = jt + c * 8;
      float sv[8];
      *(float4v*)(sv)     = *(const float4v*)(sj + j0);
      *(float4v*)(sv + 4) = *(const float4v*)(sj + j0 + 4);
      float pv[8];
#pragma unroll
      for (int q = 0; q < 8; ++q) {
        float u = Ar + sv[q];
        float v = fmaf(0.2f, sv[q], Br);
        pv[q] = exp2_fast(fmaxf(u, v));   // e^{LRelu(d_i+s_j) - m_i} in (0,1]
      }
      union { short8 s; unsigned u4[4]; } pk;
      pk.u4[0] = cvtpk_bf16(pv[0], pv[1]); pk.u4[1] = cvtpk_bf16(pv[2], pv[3]);
      pk.u4[2] = cvtpk_bf16(pv[4], pv[5]); pk.u4[3] = cvtpk_bf16(pv[6], pv[7]);
      int phys = c ^ ((iP >> 1) & 3);
      *(short8*)(Pb + iP * 32 + phys * 8) = pk.s;
    }
  };

  __syncthreads();                 // sj/ilds visible
  f32x16 acc[2][3] = {};
  stage(0, (char*)X0);
  pgen(0, P0);
  __syncthreads();                 // drains vmcnt + lgkm

  for (int tt = 0; tt < 64; ++tt) {
    unsigned short* Xc = (tt & 1) ? X1 : X0;
    unsigned short* Pc = (tt & 1) ? P1 : P0;
    if (tt < 63) {
      stage((tt + 1) * 32, (char*)((tt & 1) ? X0 : X1));
      pgen((tt + 1) * 32, (tt & 1) ? P0 : P1);
    }
#pragma unroll
    for (int kk = 0; kk < 2; ++kk) {
      short8 av[2], bv[3];
#pragma unroll
      for (int mi = 0; mi < 2; ++mi) {
        int row = wm * 64 + mi * 32 + lr;
        int sl = (kk * 2 + lh) ^ ((row >> 1) & 3);
        av[mi] = *(const short8*)(Pc + row * 32 + sl * 8);
      }
#pragma unroll
      for (int ni = 0; ni < 3; ++ni) {
        int row = wn * 96 + ni * 32 + lr;
        int sl = (kk * 2 + lh) ^ ((row >> 1) & 3);
        bv[ni] = *(const short8*)(Xc + row * 32 + sl * 8);
      }
#pragma unroll
      for (int mi = 0; mi < 2; ++mi)
#pragma unroll
        for (int ni = 0; ni < 3; ++ni)
          acc[mi][ni] = __builtin_amdgcn_mfma_f32_32x32x16_bf16(av[mi], bv[ni], acc[mi][ni], 0, 0, 0);
    }
    __syncthreads();
  }

  // epilogue: out = acc * (1/l_i) + b_gat
#pragma unroll
  for (int mi = 0; mi < 2; ++mi)
#pragma unroll
    for (int ni = 0; ni < 3; ++ni) {
      int colb = dB + wn * 96 + ni * 32 + lr;
      float bg = b_gat[colb];
#pragma unroll 16
      for (int reg = 0; reg < 16; ++reg) {
        int ml = wm * 64 + mi * 32 + 4 * lh + (reg & 3) + 8 * (reg >> 2);
        float val = fmaf(acc[mi][ni][reg], ilds[ml], bg);
        fused[(size_t)(b * S_ + mB + ml) * F_ + D_ + colb] = f2bf(val);
      }
    }
}

// ---------------- launch ----------------
extern "C" void kernel_launch(void* const* d_in, const int* in_sizes, int n_in,
                              void* d_out, int out_size, void* d_ws, size_t ws_size,
                              hipStream_t stream) {
  const float* hs   = (const float*)d_in[0];
  const float* to   = (const float*)d_in[1];
  const float* Wg   = (const float*)d_in[2];
  const float* asrc = (const float*)d_in[3];
  const float* adst = (const float*)d_in[4];
  const float* bg   = (const float*)d_in[5];
  const float* Wf   = (const float*)d_in[6];
  const float* bfu  = (const float*)d_in[7];
  float* out = (float*)d_out;

  char* ws = (char*)d_ws;
  size_t off = 0;
  auto alloc = [&](size_t bytes) {
    char* p = ws + off;
    off += (bytes + 255) & ~(size_t)255;
    return p;
  };
  unsigned short* hs_bf = (unsigned short*)alloc((size_t)BS_ * D_ * 2);
  unsigned short* xpT   = (unsigned short*)alloc((size_t)B_ * D_ * S_ * 2);
  unsigned short* fused = (unsigned short*)alloc((size_t)BS_ * F_ * 2);
  unsigned short* WgT   = (unsigned short*)alloc((size_t)D_ * D_ * 2);
  unsigned short* WfT   = (unsigned short*)alloc((size_t)D_ * F_ * 2);
  float* as   = (float*)alloc((size_t)BS_ * 4);
  float* ad   = (float*)alloc((size_t)BS_ * 4);
  float* ccA  = (float*)alloc((size_t)BS_ * 4);
  float* ccB  = (float*)alloc((size_t)BS_ * 4);
  float* ilg  = (float*)alloc((size_t)BS_ * 4);
  float* aslg = (float*)alloc((size_t)BS_ * 4);
  float* Ms   = (float*)alloc(256);

  int n = BS_ * D_;
  k_cast8<<<n / 2048, 256, 0, stream>>>(hs, hs_bf, n);
  k_cast_to_fused8<<<n / 2048, 256, 0, stream>>>(to, fused);
  k_transpose_cast<<<dim3(D_ / 32, D_ / 32), dim3(32, 8), 0, stream>>>(Wg, WgT, D_, D_);
  k_transpose_cast<<<dim3(D_ / 32, F_ / 32), dim3(32, 8), 0, stream>>>(Wf, WfT, F_, D_);
  k_gemm<1><<<dim3(6, 128), 256, 0, stream>>>(hs_bf, WgT, D_, nullptr, nullptr, xpT);
  k_alphas<<<dim3(32, B_), 256, 0, stream>>>(xpT, asrc, adst, as, ad);
  k_bmax<<<B_, 256, 0, stream>>>(as, Ms);
  k_stats<<<dim3(32, B_), 256, 0, stream>>>(as, ad, Ms, ccA, ccB, ilg, aslg);
  k_agg<<<512, 256, 0, stream>>>(xpT, ccA, ccB, ilg, aslg, bg, fused);
  k_gemm<0><<<dim3(6, 128), 256, 0, stream>>>(fused, WfT, F_, out, bfu, nullptr);
}

// Round 4
// 241.628 us; speedup vs baseline: 1.2523x; 1.0466x over previous
//
#include <hip/hip_runtime.h>
#include <hip/hip_bf16.h>
#include <stdint.h>

// ---- problem dims (fixed) ----
#define B_   8
#define S_   2048
#define D_   768
#define BS_  16384   // B_*S_
#define F_   1536    // 2*D_
#define L2E  1.4426950408889634f

typedef __attribute__((ext_vector_type(8))) short short8;    // 8 bf16 MFMA frag
typedef __attribute__((ext_vector_type(4))) float f32x4;     // 16x16 acc frag
typedef __attribute__((ext_vector_type(16))) float f32x16;   // 32x32 acc frag
typedef __attribute__((ext_vector_type(4))) float float4v;
typedef __attribute__((ext_vector_type(4))) unsigned short ushort4v;

__device__ __forceinline__ unsigned short f2bf(float f) {
  union { float f; unsigned u; } v; v.f = f;
  unsigned r = v.u + 0x7FFFu + ((v.u >> 16) & 1u);   // RNE
  return (unsigned short)(r >> 16);
}
__device__ __forceinline__ float exp2_fast(float x) {
  float r; asm("v_exp_f32 %0, %1" : "=v"(r) : "v"(x)); return r;
}
__device__ __forceinline__ unsigned cvtpk_bf16(float lo, float hi) {
  unsigned r; asm("v_cvt_pk_bf16_f32 %0, %1, %2" : "=v"(r) : "v"(lo), "v"(hi)); return r;
}

#define GLOAD16(gp, lp) \
  __builtin_amdgcn_global_load_lds((const __attribute__((address_space(1))) void*)(gp), \
                                   (__attribute__((address_space(3))) void*)(lp), 16, 0, 0)

// ---------------- cast kernels (8 elem/thread) ----------------
__global__ __launch_bounds__(256) void k_cast8(const float* __restrict__ src,
                                               unsigned short* __restrict__ dst, int n) {
  int i = (blockIdx.x * 256 + threadIdx.x) * 8;
  if (i >= n) return;
  float4v a = *(const float4v*)(src + i);
  float4v b2 = *(const float4v*)(src + i + 4);
  union { short8 s; unsigned u[4]; } o;
  o.u[0] = cvtpk_bf16(a[0], a[1]); o.u[1] = cvtpk_bf16(a[2], a[3]);
  o.u[2] = cvtpk_bf16(b2[0], b2[1]); o.u[3] = cvtpk_bf16(b2[2], b2[3]);
  *(short8*)(dst + i) = o.s;
}

__global__ __launch_bounds__(256) void k_cast_to_fused8(const float* __restrict__ to,
                                                        unsigned short* __restrict__ fused) {
  int e = (blockIdx.x * 256 + threadIdx.x) * 8;
  if (e >= BS_ * D_) return;
  int r = e / D_, c = e % D_;            // c multiple of 8
  float4v a = *(const float4v*)(to + e);
  float4v b2 = *(const float4v*)(to + e + 4);
  union { short8 s; unsigned u[4]; } o;
  o.u[0] = cvtpk_bf16(a[0], a[1]); o.u[1] = cvtpk_bf16(a[2], a[3]);
  o.u[2] = cvtpk_bf16(b2[0], b2[1]); o.u[3] = cvtpk_bf16(b2[2], b2[3]);
  *(short8*)(fused + (size_t)r * F_ + c) = o.s;
}

// src[R][C] f32 -> dst[C][R] bf16   (R,C multiples of 32)
__global__ __launch_bounds__(256) void k_transpose_cast(const float* __restrict__ src,
                                                        unsigned short* __restrict__ dst,
                                                        int R, int C) {
  __shared__ float tile[32][33];
  int bx = blockIdx.x * 32;   // C index
  int by = blockIdx.y * 32;   // R index
  int tx = threadIdx.x, ty = threadIdx.y;   // block (32,8)
#pragma unroll
  for (int k = 0; k < 32; k += 8)
    tile[ty + k][tx] = src[(size_t)(by + ty + k) * C + bx + tx];
  __syncthreads();
#pragma unroll
  for (int k = 0; k < 32; k += 8)
    dst[(size_t)(bx + ty + k) * R + by + tx] = f2bf(tile[tx][ty + k]);
}

// ---------------- GEMM v2: C[M][768] = A[M][K] * BT[768][K]^T ----------------
// BK=64 (128B rows, T2 c^(r&7) swizzle), double-buffered LDS (64KB), counted
// vmcnt(8) + raw barriers (loads stay in flight across barriers), setprio.
// EPI=0: f32 out + bias.  EPI=1: transpose-epilogue -> xpT[b][d][s] bf16.
template <int EPI>
__global__ __launch_bounds__(256, 2) void k_gemm(const unsigned short* __restrict__ A,
                                                 const unsigned short* __restrict__ BT,
                                                 int K,
                                                 float* __restrict__ outF,
                                                 const float* __restrict__ bias,
                                                 unsigned short* __restrict__ outT) {
  __shared__ unsigned short smem[32768];   // A0 B0 A1 B1, each [128][64]
  int lin = blockIdx.x;                    // 768 blocks, 768%8==0 -> bijective XCD chunk
  int nl  = (lin & 7) * 96 + (lin >> 3);
  int mBase = (nl / 6) * 128;
  int nBase = (nl % 6) * 128;
  int t = threadIdx.x;
  int w = t >> 6, l = t & 63;
  int lm = l & 15, lg = l >> 4;
  int wm = w >> 1, wn = w & 1;   // 2x2 waves, 64x64 per wave
  f32x4 acc[4][4] = {};
  const int KT = K >> 6;

  auto stage = [&](int kt, int half) {
    unsigned short* Ab = smem + half * 16384;
    unsigned short* Bb = Ab + 8192;
#pragma unroll
    for (int i = 0; i < 4; ++i) {
      int g = i * 256 + t;
      int r = g >> 3;
      int c = (g & 7) ^ (r & 7);           // pre-swizzled source chunk
      GLOAD16(A  + (size_t)(mBase + r) * K + kt + c * 8, (char*)Ab + i * 4096 + w * 1024);
      GLOAD16(BT + (size_t)(nBase + r) * K + kt + c * 8, (char*)Bb + i * 4096 + w * 1024);
    }
  };

  stage(0, 0);
  for (int kt = 0; kt < KT; ++kt) {
    int half = kt & 1;
    if (kt + 1 < KT) {
      stage((kt + 1) * 64, half ^ 1);
      asm volatile("s_waitcnt vmcnt(8)" ::: "memory");   // prev stage landed; ours in flight
    } else {
      asm volatile("s_waitcnt vmcnt(0)" ::: "memory");
    }
    __builtin_amdgcn_s_barrier();
    __builtin_amdgcn_sched_barrier(0);
    unsigned short* Ab = smem + half * 16384;
    unsigned short* Bb = Ab + 8192;
    __builtin_amdgcn_s_setprio(1);
#pragma unroll
    for (int ks = 0; ks < 2; ++ks) {
      short8 af[4], bfr[4];
#pragma unroll
      for (int mi = 0; mi < 4; ++mi) {
        int r = wm * 64 + mi * 16 + lm;
        int c = (ks * 4 + lg) ^ (r & 7);
        af[mi] = *(const short8*)(Ab + r * 64 + c * 8);
      }
#pragma unroll
      for (int ni = 0; ni < 4; ++ni) {
        int r = wn * 64 + ni * 16 + lm;
        int c = (ks * 4 + lg) ^ (r & 7);
        bfr[ni] = *(const short8*)(Bb + r * 64 + c * 8);
      }
#pragma unroll
      for (int mi = 0; mi < 4; ++mi)
#pragma unroll
        for (int ni = 0; ni < 4; ++ni)
          acc[mi][ni] = __builtin_amdgcn_mfma_f32_16x16x32_bf16(af[mi], bfr[ni], acc[mi][ni], 0, 0, 0);
    }
    __builtin_amdgcn_s_setprio(0);
    __builtin_amdgcn_sched_barrier(0);
    __builtin_amdgcn_s_barrier();
  }

  if (EPI == 0) {
#pragma unroll
    for (int mi = 0; mi < 4; ++mi) {
      int m = mBase + wm * 64 + mi * 16 + lg * 4;
#pragma unroll
      for (int ni = 0; ni < 4; ++ni) {
        int n = nBase + wn * 64 + ni * 16 + lm;
        float bv = bias[n];
#pragma unroll
        for (int r = 0; r < 4; ++r)
          outF[(size_t)(m + r) * 768 + n] = acc[mi][ni][r] + bv;
      }
    }
  } else {
    // write acc into smem as [n][m] bf16, then store xpT rows coalesced
#pragma unroll
    for (int mi = 0; mi < 4; ++mi) {
#pragma unroll
      for (int ni = 0; ni < 4; ++ni) {
        int nl2 = wn * 64 + ni * 16 + lm;
        int ml = wm * 64 + mi * 16 + lg * 4;
        ushort4v o;
        o[0] = f2bf(acc[mi][ni][0]); o[1] = f2bf(acc[mi][ni][1]);
        o[2] = f2bf(acc[mi][ni][2]); o[3] = f2bf(acc[mi][ni][3]);
        *(ushort4v*)(&smem[nl2 * 128 + ml]) = o;
      }
    }
    __syncthreads();
    int b = mBase >> 11;
    int sBase = mBase & 2047;
#pragma unroll
    for (int it = 0; it < 8; ++it) {
      int nRow = it * 16 + (t >> 4);
      int m0 = (t & 15) * 8;
      short8 v = *(const short8*)(&smem[nRow * 128 + m0]);
      *(short8*)(outT + ((size_t)b * D_ + nBase + nRow) * S_ + sBase + m0) = v;
    }
  }
}

// ---------------- alphas ----------------
__global__ __launch_bounds__(256) void k_alphas(const unsigned short* __restrict__ xpT,
                                                const float* __restrict__ a_src,
                                                const float* __restrict__ a_dst,
                                                float* __restrict__ as, float* __restrict__ ad) {
  __shared__ float rs[4][64], rd[4][64];
  int b = blockIdx.y;
  int sl = threadIdx.x & 63, part = threadIdx.x >> 6;
  int s = blockIdx.x * 64 + sl;
  const unsigned short* p = xpT + (size_t)b * D_ * S_ + s;
  float accs = 0.f, accd = 0.f;
  for (int d = part * 192; d < part * 192 + 192; ++d) {
    union { unsigned u; float f; } v; v.u = ((unsigned)p[(size_t)d * S_]) << 16;
    accs = fmaf(a_src[d], v.f, accs);
    accd = fmaf(a_dst[d], v.f, accd);
  }
  rs[part][sl] = accs; rd[part][sl] = accd;
  __syncthreads();
  if (threadIdx.x < 64) {
    int tt = threadIdx.x;
    as[b * S_ + blockIdx.x * 64 + tt] = rs[0][tt] + rs[1][tt] + rs[2][tt] + rs[3][tt];
    ad[b * S_ + blockIdx.x * 64 + tt] = rd[0][tt] + rd[1][tt] + rd[2][tt] + rd[3][tt];
  }
}

// per-batch max of alpha_src
__global__ __launch_bounds__(256) void k_bmax(const float* __restrict__ as, float* __restrict__ Ms) {
  __shared__ float red[256];
  int b = blockIdx.x, t = threadIdx.x;
  float m = -1e30f;
#pragma unroll
  for (int k = 0; k < 8; ++k) m = fmaxf(m, as[b * S_ + t + k * 256]);
  red[t] = m;
  __syncthreads();
  for (int st = 128; st > 0; st >>= 1) {
    if (t < st) red[t] = fmaxf(red[t], red[t + st]);
    __syncthreads();
  }
  if (t == 0) Ms[b] = red[0];
}

// stats: ccA=(d_i-m_i)*L2E, ccB=(0.2d_i-m_i)*L2E, il=1/l_i, aslg=as*L2E
__global__ __launch_bounds__(256) void k_stats(const float* __restrict__ as,
                                               const float* __restrict__ ad,
                                               const float* __restrict__ Ms,
                                               float* __restrict__ ccA, float* __restrict__ ccB,
                                               float* __restrict__ il, float* __restrict__ aslg) {
  __shared__ float sjl[S_];
  __shared__ float red[4][64];
  int b = blockIdx.y;
  int t = threadIdx.x;
#pragma unroll
  for (int k = 0; k < 8; ++k) sjl[t + k * 256] = as[b * S_ + t + k * 256];
  __syncthreads();
  int ilc = t & 63, part = t >> 6;
  int i = blockIdx.x * 64 + ilc;
  float di = ad[b * S_ + i];
  float xm = di + Ms[b];
  float mi = fmaxf(xm, 0.2f * xm);
  float lsum = 0.f;
  for (int j = part * 512; j < part * 512 + 512; ++j) {
    float x = di + sjl[j];
    float z = fmaxf(x, 0.2f * x);
    lsum += __expf(z - mi);
  }
  red[part][ilc] = lsum;
  __syncthreads();
  if (t < 64) {
    int ig = blockIdx.x * 64 + t;      // part==0 -> own di, mi valid
    float lt = red[0][t] + red[1][t] + red[2][t] + red[3][t];
    il[b * S_ + ig] = 1.0f / lt;
    ccA[b * S_ + ig] = (di - mi) * L2E;
    ccB[b * S_ + ig] = fmaf(0.2f, di, -mi) * L2E;
    aslg[b * S_ + ig] = sjl[ig] * L2E;
  }
}

// ---------------- aggregation v5: counted-vmcnt 2-phase pipeline ----------------
// 256 thr (4 waves, n-split), block 64i x 384d, wave 64i x 96d = M2xN3 of 32x32x16.
// BK=32, X/P double-buffered, 1/l folded into P, grid 512 = 2 blocks/CU.
__global__ __launch_bounds__(256, 2) void k_agg(const unsigned short* __restrict__ xpT,
                                                const float* __restrict__ ccA,
                                                const float* __restrict__ ccB,
                                                const float* __restrict__ ilg,
                                                const float* __restrict__ aslg,
                                                const float* __restrict__ b_gat,
                                                unsigned short* __restrict__ fused) {
  __shared__ unsigned short X0[384 * 32], X1[384 * 32];   // 24KB each
  __shared__ unsigned short P0[64 * 32], P1[64 * 32];     // 4KB each
  __shared__ float sj[S_];                                 // 8KB  (total 64KB)

  int bid = blockIdx.x;          // 512 blocks; bid&7 = batch -> per-XCD L2 locality
  int b = bid & 7;
  int within = bid >> 3;         // 0..63
  int mB = (within & 31) * 64;
  int dB = (within >> 5) * 384;

  int t = threadIdx.x;
  int w = t >> 6, l = t & 63;
  int lr = l & 31, lh = l >> 5;
  int wn = w;                    // 4 waves n-split: d in [wn*96, wn*96+96)

  // stage scaled alpha_src row
  {
    float4v v0 = *(const float4v*)(aslg + b * S_ + t * 8);
    float4v v1 = *(const float4v*)(aslg + b * S_ + t * 8 + 4);
    *(float4v*)(sj + t * 8) = v0;
    *(float4v*)(sj + t * 8 + 4) = v1;
  }

  // pgen constants: thread t handles P row t>>2, chunk t&3
  int rP = t >> 2, cP = t & 3;
  float Ar = ccA[b * S_ + mB + rP];
  float Br = ccB[b * S_ + mB + rP];
  float Ir = ilg[b * S_ + mB + rP];

  const unsigned short* Xsrc = xpT + ((size_t)b * D_ + dB) * S_;

  auto stage = [&](int jt, char* Xb) {
#pragma unroll
    for (int is = 0; is < 6; ++is) {
      int g = is * 256 + t;            // 1536 slots = 384 rows x 4 chunks
      int r = g >> 2, p = g & 3;
      int c = p ^ ((r >> 1) & 3);      // logical j-chunk for this physical slot
      GLOAD16(Xsrc + (size_t)r * S_ + jt + c * 8, Xb + is * 4096 + w * 1024);
    }
  };
  auto pgen = [&](int jt, unsigned short* Pb) {
    int j0 = jt + cP * 8;
    float sv[8];
    *(float4v*)(sv)     = *(const float4v*)(sj + j0);
    *(float4v*)(sv + 4) = *(const float4v*)(sj + j0 + 4);
    float pv[8];
#pragma unroll
    for (int q = 0; q < 8; ++q) {
      float u = Ar + sv[q];
      float v = fmaf(0.2f, sv[q], Br);
      pv[q] = exp2_fast(fmaxf(u, v)) * Ir;   // attn weight in (0,1]
    }
    union { short8 s; unsigned u4[4]; } pk;
    pk.u4[0] = cvtpk_bf16(pv[0], pv[1]); pk.u4[1] = cvtpk_bf16(pv[2], pv[3]);
    pk.u4[2] = cvtpk_bf16(pv[4], pv[5]); pk.u4[3] = cvtpk_bf16(pv[6], pv[7]);
    int phys = cP ^ ((rP >> 1) & 3);
    *(short8*)(Pb + rP * 32 + phys * 8) = pk.s;
  };

  __syncthreads();                 // sj visible to all pgen threads
  f32x16 acc[2][3] = {};
  stage(0, (char*)X0);
  pgen(0, P0);
  asm volatile("s_waitcnt vmcnt(0) lgkmcnt(0)" ::: "memory");
  __builtin_amdgcn_s_barrier();
  __builtin_amdgcn_sched_barrier(0);

  for (int tt = 0; tt < 64; ++tt) {
    unsigned short* Xc = (tt & 1) ? X1 : X0;
    unsigned short* Pc = (tt & 1) ? P1 : P0;
    if (tt < 63) {
      stage((tt + 1) * 32, (char*)((tt & 1) ? X0 : X1));
      pgen((tt + 1) * 32, (tt & 1) ? P0 : P1);
      asm volatile("s_waitcnt vmcnt(6) lgkmcnt(0)" ::: "memory");  // prev stage landed
    } else {
      asm volatile("s_waitcnt vmcnt(0) lgkmcnt(0)" ::: "memory");
    }
    __builtin_amdgcn_s_barrier();        // B1: X/P of this step published
    __builtin_amdgcn_sched_barrier(0);
    __builtin_amdgcn_s_setprio(1);
#pragma unroll
    for (int ks = 0; ks < 2; ++ks) {
      short8 av[2], bv[3];
#pragma unroll
      for (int mi = 0; mi < 2; ++mi) {
        int row = mi * 32 + lr;
        int c = (ks * 2 + lh) ^ ((row >> 1) & 3);
        av[mi] = *(const short8*)(Pc + row * 32 + c * 8);
      }
#pragma unroll
      for (int ni = 0; ni < 3; ++ni) {
        int row = wn * 96 + ni * 32 + lr;
        int c = (ks * 2 + lh) ^ ((row >> 1) & 3);
        bv[ni] = *(const short8*)(Xc + row * 32 + c * 8);
      }
#pragma unroll
      for (int mi = 0; mi < 2; ++mi)
#pragma unroll
        for (int ni = 0; ni < 3; ++ni)
          acc[mi][ni] = __builtin_amdgcn_mfma_f32_32x32x16_bf16(av[mi], bv[ni], acc[mi][ni], 0, 0, 0);
    }
    __builtin_amdgcn_s_setprio(0);
    __builtin_amdgcn_sched_barrier(0);
    __builtin_amdgcn_s_barrier();        // B2: reads done before next restage
  }

  // epilogue: out = acc + b_gat   (1/l already folded into P)
#pragma unroll
  for (int mi = 0; mi < 2; ++mi)
#pragma unroll
    for (int ni = 0; ni < 3; ++ni) {
      int colb = dB + wn * 96 + ni * 32 + lr;
      float bg = b_gat[colb];
#pragma unroll 16
      for (int reg = 0; reg < 16; ++reg) {
        int ml = mi * 32 + 4 * lh + (reg & 3) + 8 * (reg >> 2);
        fused[(size_t)(b * S_ + mB + ml) * F_ + D_ + colb] = f2bf(acc[mi][ni][reg] + bg);
      }
    }
}

// ---------------- launch ----------------
extern "C" void kernel_launch(void* const* d_in, const int* in_sizes, int n_in,
                              void* d_out, int out_size, void* d_ws, size_t ws_size,
                              hipStream_t stream) {
  const float* hs   = (const float*)d_in[0];
  const float* to   = (const float*)d_in[1];
  const float* Wg   = (const float*)d_in[2];
  const float* asrc = (const float*)d_in[3];
  const float* adst = (const float*)d_in[4];
  const float* bg   = (const float*)d_in[5];
  const float* Wf   = (const float*)d_in[6];
  const float* bfu  = (const float*)d_in[7];
  float* out = (float*)d_out;

  char* ws = (char*)d_ws;
  size_t off = 0;
  auto alloc = [&](size_t bytes) {
    char* p = ws + off;
    off += (bytes + 255) & ~(size_t)255;
    return p;
  };
  unsigned short* hs_bf = (unsigned short*)alloc((size_t)BS_ * D_ * 2);
  unsigned short* xpT   = (unsigned short*)alloc((size_t)B_ * D_ * S_ * 2);
  unsigned short* fused = (unsigned short*)alloc((size_t)BS_ * F_ * 2);
  unsigned short* WgT   = (unsigned short*)alloc((size_t)D_ * D_ * 2);
  unsigned short* WfT   = (unsigned short*)alloc((size_t)D_ * F_ * 2);
  float* as   = (float*)alloc((size_t)BS_ * 4);
  float* ad   = (float*)alloc((size_t)BS_ * 4);
  float* ccA  = (float*)alloc((size_t)BS_ * 4);
  float* ccB  = (float*)alloc((size_t)BS_ * 4);
  float* ilg  = (float*)alloc((size_t)BS_ * 4);
  float* aslg = (float*)alloc((size_t)BS_ * 4);
  float* Ms   = (float*)alloc(256);

  int n = BS_ * D_;
  k_cast8<<<n / 2048, 256, 0, stream>>>(hs, hs_bf, n);
  k_cast_to_fused8<<<n / 2048, 256, 0, stream>>>(to, fused);
  k_transpose_cast<<<dim3(D_ / 32, D_ / 32), dim3(32, 8), 0, stream>>>(Wg, WgT, D_, D_);
  k_transpose_cast<<<dim3(D_ / 32, F_ / 32), dim3(32, 8), 0, stream>>>(Wf, WfT, F_, D_);
  k_gemm<1><<<768, 256, 0, stream>>>(hs_bf, WgT, D_, nullptr, nullptr, xpT);
  k_alphas<<<dim3(32, B_), 256, 0, stream>>>(xpT, asrc, adst, as, ad);
  k_bmax<<<B_, 256, 0, stream>>>(as, Ms);
  k_stats<<<dim3(32, B_), 256, 0, stream>>>(as, ad, Ms, ccA, ccB, ilg, aslg);
  k_agg<<<512, 256, 0, stream>>>(xpT, ccA, ccB, ilg, aslg, bg, fused);
  k_gemm<0><<<768, 256, 0, stream>>>(fused, WfT, F_, out, bfu, nullptr);
}